// Round 3
// baseline (19866.116 us; speedup 1.0000x reference)
//
#include <hip/hip_runtime.h>
#include <hip/hip_cooperative_groups.h>

namespace cg = cooperative_groups;

constexpr int   T_     = 256;
constexpr int   N_     = 64;
constexpr int   H_     = 512;
constexpr float DT_    = 0.01f;
constexpr float GAMMA_ = 1.0f;
constexpr float EPS_   = 1.0f;

constexpr int GRID  = 512;          // 8 WGs per network, 2 WG/CU co-resident
constexpr int BLOCK = 256;          // 4 waves
constexpr int WGPN  = GRID / N_;    // 8 workgroups per network
constexpr int ROWS  = H_ / WGPN;    // 64 rows of W_h and W_x per workgroup

// One timestep's work for workgroup (n, q). Reads states_all[t], writes
// states_all[t+1] (its 64 rows) and ins_all[t+1] (its 64-wide h-slice).
__device__ __forceinline__ void step_body(
    int t, int n, int q, int tid, int lane, int wave,
    const float* __restrict__ x, const float* __restrict__ conn,
    const float* __restrict__ W_h, const float* __restrict__ W_x,
    const float* __restrict__ bias,
    float* __restrict__ states_all, float* __restrict__ ins_all,
    float* s_hy, float* s_ins, float* s_pre)
{
    const float* st_t = states_all + (size_t)t * N_ * 2 * H_;
    const float* xt   = x + (size_t)t * N_ * H_;

    // ---- Phase A: ins[h] = (conn[n,:] . outs[:,h]) * x_t[n,h]
    //      outs = hy_t for t>0, zeros for t==0 (reference init_outs).
    //      Computed redundantly by all 8 WGs of a network (st_t is 256 KB,
    //      L2-resident) so only ONE barrier per step is needed.
    {
        const int h0 = tid, h1 = tid + 256;
        float i0 = 0.f, i1 = 0.f;
        if (t > 0) {
            float a0 = 0.f, a1 = 0.f;
            #pragma unroll 8
            for (int m = 0; m < N_; ++m) {
                const float c   = conn[n * N_ + m];
                const float* hm = st_t + m * 2 * H_;   // hy row of network m
                a0 += c * hm[h0];
                a1 += c * hm[h1];
            }
            i0 = a0 * xt[n * H_ + h0];
            i1 = a1 * xt[n * H_ + h1];
        }
        s_ins[h0] = i0;
        s_ins[h1] = i1;
        s_hy[h0] = st_t[n * 2 * H_ + h0];
        s_hy[h1] = st_t[n * 2 * H_ + h1];
        float* insd = ins_all + (size_t)(t + 1) * N_ * H_ + n * H_;
        if ((h0 >> 6) == q) insd[h0] = i0;
        if ((h1 >> 6) == q) insd[h1] = i1;
    }
    __syncthreads();

    // ---- Phase B: pre[i] = W_h[n,i,:].hy + W_x[n,i,:].ins  (rows q*64..)
    //      wave-wide dot: lane covers 4 cols via float4, 2 iters = 512 cols
    {
        const float4* vh = (const float4*)s_hy;
        const float4* vi = (const float4*)s_ins;
        for (int rl = wave; rl < ROWS; rl += 4) {
            const int i = q * ROWS + rl;
            const float4* wh = (const float4*)(W_h + ((size_t)n * H_ + i) * H_);
            const float4* wx = (const float4*)(W_x + ((size_t)n * H_ + i) * H_);
            float acc = 0.f;
            #pragma unroll
            for (int k = 0; k < 2; ++k) {
                const float4 a = wh[k * 64 + lane];
                const float4 v = vh[k * 64 + lane];
                acc += a.x * v.x + a.y * v.y + a.z * v.z + a.w * v.w;
                const float4 c4 = wx[k * 64 + lane];
                const float4 u = vi[k * 64 + lane];
                acc += c4.x * u.x + c4.y * u.y + c4.z * u.z + c4.w * u.w;
            }
            #pragma unroll
            for (int off = 32; off; off >>= 1)
                acc += __shfl_xor(acc, off);
            if (lane == 0) s_pre[rl] = acc;
        }
    }
    __syncthreads();

    // ---- Phase C: state update for this WG's 64 rows ----
    if (tid < ROWS) {
        const int i   = q * ROWS + tid;
        const float pre  = s_pre[tid] + bias[n * H_ + i];
        const float hy   = st_t[n * 2 * H_ + i];
        const float hz   = st_t[n * 2 * H_ + H_ + i];
        const float th   = tanhf(pre);
        const float hz_n = hz + DT_ * (th - GAMMA_ * hy - EPS_ * hz);
        const float hy_n = hy + DT_ * hz_n;
        float* st1 = states_all + (size_t)(t + 1) * N_ * 2 * H_ + n * 2 * H_;
        st1[i]      = hy_n;
        st1[H_ + i] = hz_n;
    }
}

// ---------- primary path: one persistent cooperative kernel ----------
__global__ __launch_bounds__(BLOCK, 2)
void archetypes_persistent(const float* __restrict__ x,
                           const float* __restrict__ conn,
                           const float* __restrict__ W_h,
                           const float* __restrict__ W_x,
                           const float* __restrict__ bias,
                           const float* __restrict__ init_states,
                           float* __restrict__ out)
{
    cg::grid_group grid = cg::this_grid();

    const int tid  = threadIdx.x;
    const int wg   = blockIdx.x;
    const int n    = wg >> 3;
    const int q    = wg & 7;
    const int lane = tid & 63;
    const int wave = tid >> 6;

    float* states_all = out;                                   // (T+1, N, 2, H)
    float* ins_all    = out + (size_t)(T_ + 1) * N_ * 2 * H_;  // (T+1, N, H)

    __shared__ float s_hy[H_];
    __shared__ float s_ins[H_];
    __shared__ float s_pre[ROWS];

    for (int idx = wg * BLOCK + tid; idx < N_ * 2 * H_; idx += GRID * BLOCK)
        states_all[idx] = init_states[idx];
    for (int idx = wg * BLOCK + tid; idx < N_ * H_; idx += GRID * BLOCK)
        ins_all[idx] = x[idx];

    grid.sync();

    for (int t = 0; t < T_; ++t) {
        step_body(t, n, q, tid, lane, wave, x, conn, W_h, W_x, bias,
                  states_all, ins_all, s_hy, s_ins, s_pre);
        grid.sync();   // states_all[t+1] visible to all XCDs before next step
    }
}

// ---------- fallback path: per-step kernels, stream-ordered ----------
__global__ __launch_bounds__(BLOCK)
void archetypes_init(const float* __restrict__ x,
                     const float* __restrict__ init_states,
                     float* __restrict__ out)
{
    float* states_all = out;
    float* ins_all    = out + (size_t)(T_ + 1) * N_ * 2 * H_;
    const int idx = blockIdx.x * BLOCK + threadIdx.x;
    if (idx < N_ * 2 * H_) states_all[idx] = init_states[idx];
    if (idx < N_ * H_)     ins_all[idx]    = x[idx];
}

__global__ __launch_bounds__(BLOCK)
void archetypes_step(int t,
                     const float* __restrict__ x,
                     const float* __restrict__ conn,
                     const float* __restrict__ W_h,
                     const float* __restrict__ W_x,
                     const float* __restrict__ bias,
                     float* __restrict__ out)
{
    const int tid  = threadIdx.x;
    const int wg   = blockIdx.x;
    const int n    = wg >> 3;
    const int q    = wg & 7;
    const int lane = tid & 63;
    const int wave = tid >> 6;

    float* states_all = out;
    float* ins_all    = out + (size_t)(T_ + 1) * N_ * 2 * H_;

    __shared__ float s_hy[H_];
    __shared__ float s_ins[H_];
    __shared__ float s_pre[ROWS];

    step_body(t, n, q, tid, lane, wave, x, conn, W_h, W_x, bias,
              states_all, ins_all, s_hy, s_ins, s_pre);
}

extern "C" void kernel_launch(void* const* d_in, const int* in_sizes, int n_in,
                              void* d_out, int out_size, void* d_ws, size_t ws_size,
                              hipStream_t stream) {
    const float* x     = (const float*)d_in[0];
    const float* conn  = (const float*)d_in[1];
    const float* W_h   = (const float*)d_in[2];
    const float* W_x   = (const float*)d_in[3];
    const float* bias  = (const float*)d_in[4];
    const float* inits = (const float*)d_in[5];
    float*       outp  = (float*)d_out;

    // Capture-safe, deterministic host-side occupancy gate: only take the
    // cooperative path if all 512 WGs are provably co-resident.
    int perCU = 0;
    (void)hipOccupancyMaxActiveBlocksPerMultiprocessor(
        &perCU, (const void*)archetypes_persistent, BLOCK, 0);
    const bool coop_ok = (perCU * 256 >= GRID);

    if (coop_ok) {
        void* args[] = {(void*)&x, (void*)&conn, (void*)&W_h, (void*)&W_x,
                        (void*)&bias, (void*)&inits, (void*)&outp};
        hipLaunchCooperativeKernel((void*)archetypes_persistent,
                                   dim3(GRID), dim3(BLOCK), args, 0, stream);
    } else {
        archetypes_init<<<dim3((N_ * 2 * H_ + BLOCK - 1) / BLOCK), dim3(BLOCK),
                          0, stream>>>(x, inits, outp);
        for (int t = 0; t < T_; ++t)
            archetypes_step<<<dim3(GRID), dim3(BLOCK), 0, stream>>>(
                t, x, conn, W_h, W_x, bias, outp);
    }
}

// Round 4
// 7099.259 us; speedup vs baseline: 2.7983x; 2.7983x over previous
//
#include <hip/hip_runtime.h>
#include <hip/hip_cooperative_groups.h>

namespace cg = cooperative_groups;

constexpr int   T_     = 256;
constexpr int   N_     = 64;
constexpr int   H_     = 512;
constexpr float DT_    = 0.01f;
constexpr float GAMMA_ = 1.0f;
constexpr float EPS_   = 1.0f;

constexpr int GRID  = 2048;         // 32 WGs per network, 8 WG/CU -> 32 waves/CU
constexpr int BLOCK = 256;          // 4 waves
constexpr int WGPN  = GRID / N_;    // 32 workgroups per network
constexpr int ROWS  = H_ / WGPN;    // 16 rows of W_h and W_x per workgroup

// One timestep's work for workgroup (n, q). Reads states_all[t], writes
// states_all[t+1] (its ROWS rows) and ins_all[t+1] (its ROWS-wide h-slice).
// s_conn (64 floats, conn[n,:]) and s_bias (ROWS floats) must be pre-staged.
__device__ __forceinline__ void step_body(
    int t, int n, int q, int tid, int lane, int wave,
    const float* __restrict__ x,
    const float* __restrict__ W_h, const float* __restrict__ W_x,
    float* __restrict__ states_all, float* __restrict__ ins_all,
    float* s_hy, float* s_ins, float* s_pre,
    const float* s_conn, const float* s_bias)
{
    const float* st_t = states_all + (size_t)t * N_ * 2 * H_;
    const float* xt   = x + (size_t)t * N_ * H_;

    // ---- Phase A: ins[h] = (conn[n,:] . outs[:,h]) * x_t[n,h]
    //      outs = hy_t for t>0, zeros for t==0 (reference init_outs).
    //      Redundant across the network's WGs (hy panel is L2-resident) so
    //      only ONE grid-wide barrier per step is needed.
    {
        const int h0 = tid, h1 = tid + 256;
        float i0 = 0.f, i1 = 0.f;
        if (t > 0) {
            float a0 = 0.f, a1 = 0.f;
            #pragma unroll 8
            for (int m = 0; m < N_; ++m) {
                const float c   = s_conn[m];
                const float* hm = st_t + m * 2 * H_;   // hy row of network m
                a0 += c * hm[h0];
                a1 += c * hm[h1];
            }
            i0 = a0 * xt[n * H_ + h0];
            i1 = a1 * xt[n * H_ + h1];
        }
        s_ins[h0] = i0;
        s_ins[h1] = i1;
        s_hy[h0] = st_t[n * 2 * H_ + h0];
        s_hy[h1] = st_t[n * 2 * H_ + h1];
        // each WG writes its own ROWS-wide h-slice of ins_all[t+1]
        float* insd = ins_all + (size_t)(t + 1) * N_ * H_ + n * H_;
        if (h0 / ROWS == q) insd[h0] = i0;
        if (h1 / ROWS == q) insd[h1] = i1;
    }
    __syncthreads();

    // ---- Phase B: pre[i] = W_h[n,i,:].hy + W_x[n,i,:].ins  (rows q*ROWS..)
    //      wave-wide dot: lane covers 4 cols via float4, 2 iters = 512 cols
    {
        const float4* vh = (const float4*)s_hy;
        const float4* vi = (const float4*)s_ins;
        for (int rl = wave; rl < ROWS; rl += 4) {
            const int i = q * ROWS + rl;
            const float4* wh = (const float4*)(W_h + ((size_t)n * H_ + i) * H_);
            const float4* wx = (const float4*)(W_x + ((size_t)n * H_ + i) * H_);
            float acc = 0.f;
            #pragma unroll
            for (int k = 0; k < 2; ++k) {
                const float4 a = wh[k * 64 + lane];
                const float4 v = vh[k * 64 + lane];
                acc += a.x * v.x + a.y * v.y + a.z * v.z + a.w * v.w;
                const float4 c4 = wx[k * 64 + lane];
                const float4 u = vi[k * 64 + lane];
                acc += c4.x * u.x + c4.y * u.y + c4.z * u.z + c4.w * u.w;
            }
            #pragma unroll
            for (int off = 32; off; off >>= 1)
                acc += __shfl_xor(acc, off);
            if (lane == 0) s_pre[rl] = acc;
        }
    }
    __syncthreads();

    // ---- Phase C: state update for this WG's ROWS rows ----
    if (tid < ROWS) {
        const int i   = q * ROWS + tid;
        const float pre  = s_pre[tid] + s_bias[tid];
        const float hy   = st_t[n * 2 * H_ + i];
        const float hz   = st_t[n * 2 * H_ + H_ + i];
        const float th   = tanhf(pre);
        const float hz_n = hz + DT_ * (th - GAMMA_ * hy - EPS_ * hz);
        const float hy_n = hy + DT_ * hz_n;
        float* st1 = states_all + (size_t)(t + 1) * N_ * 2 * H_ + n * 2 * H_;
        st1[i]      = hy_n;
        st1[H_ + i] = hz_n;
    }
}

// ---------- primary path: one persistent cooperative kernel ----------
__global__ __launch_bounds__(BLOCK, 8)
void archetypes_persistent(const float* __restrict__ x,
                           const float* __restrict__ conn,
                           const float* __restrict__ W_h,
                           const float* __restrict__ W_x,
                           const float* __restrict__ bias,
                           const float* __restrict__ init_states,
                           float* __restrict__ out)
{
    cg::grid_group grid = cg::this_grid();

    const int tid  = threadIdx.x;
    const int wg   = blockIdx.x;
    const int n    = wg / WGPN;
    const int q    = wg % WGPN;
    const int lane = tid & 63;
    const int wave = tid >> 6;

    float* states_all = out;                                   // (T+1, N, 2, H)
    float* ins_all    = out + (size_t)(T_ + 1) * N_ * 2 * H_;  // (T+1, N, H)

    __shared__ float s_hy[H_];
    __shared__ float s_ins[H_];
    __shared__ float s_pre[ROWS];
    __shared__ float s_conn[N_];
    __shared__ float s_bias[ROWS];

    // stage invariants once
    if (tid < N_)   s_conn[tid] = conn[n * N_ + tid];
    if (tid < ROWS) s_bias[tid] = bias[n * H_ + q * ROWS + tid];

    for (int idx = wg * BLOCK + tid; idx < N_ * 2 * H_; idx += GRID * BLOCK)
        states_all[idx] = init_states[idx];
    for (int idx = wg * BLOCK + tid; idx < N_ * H_; idx += GRID * BLOCK)
        ins_all[idx] = x[idx];

    grid.sync();   // also orders the s_conn/s_bias stores for this block

    for (int t = 0; t < T_; ++t) {
        step_body(t, n, q, tid, lane, wave, x, W_h, W_x,
                  states_all, ins_all, s_hy, s_ins, s_pre, s_conn, s_bias);
        grid.sync();   // states_all[t+1] visible to all XCDs before next step
    }
}

// ---------- fallback path: per-step kernels, stream-ordered ----------
__global__ __launch_bounds__(BLOCK)
void archetypes_init(const float* __restrict__ x,
                     const float* __restrict__ init_states,
                     float* __restrict__ out)
{
    float* states_all = out;
    float* ins_all    = out + (size_t)(T_ + 1) * N_ * 2 * H_;
    const int idx = blockIdx.x * BLOCK + threadIdx.x;
    if (idx < N_ * 2 * H_) states_all[idx] = init_states[idx];
    if (idx < N_ * H_)     ins_all[idx]    = x[idx];
}

__global__ __launch_bounds__(BLOCK)
void archetypes_step(int t,
                     const float* __restrict__ x,
                     const float* __restrict__ conn,
                     const float* __restrict__ W_h,
                     const float* __restrict__ W_x,
                     const float* __restrict__ bias,
                     float* __restrict__ out)
{
    const int tid  = threadIdx.x;
    const int wg   = blockIdx.x;
    const int n    = wg / WGPN;
    const int q    = wg % WGPN;
    const int lane = tid & 63;
    const int wave = tid >> 6;

    float* states_all = out;
    float* ins_all    = out + (size_t)(T_ + 1) * N_ * 2 * H_;

    __shared__ float s_hy[H_];
    __shared__ float s_ins[H_];
    __shared__ float s_pre[ROWS];
    __shared__ float s_conn[N_];
    __shared__ float s_bias[ROWS];

    if (tid < N_)   s_conn[tid] = conn[n * N_ + tid];
    if (tid < ROWS) s_bias[tid] = bias[n * H_ + q * ROWS + tid];
    __syncthreads();

    step_body(t, n, q, tid, lane, wave, x, W_h, W_x,
              states_all, ins_all, s_hy, s_ins, s_pre, s_conn, s_bias);
}

extern "C" void kernel_launch(void* const* d_in, const int* in_sizes, int n_in,
                              void* d_out, int out_size, void* d_ws, size_t ws_size,
                              hipStream_t stream) {
    const float* x     = (const float*)d_in[0];
    const float* conn  = (const float*)d_in[1];
    const float* W_h   = (const float*)d_in[2];
    const float* W_x   = (const float*)d_in[3];
    const float* bias  = (const float*)d_in[4];
    const float* inits = (const float*)d_in[5];
    float*       outp  = (float*)d_out;

    // Capture-safe, deterministic host-side occupancy gate: only take the
    // cooperative path if all GRID WGs are provably co-resident.
    int perCU = 0;
    (void)hipOccupancyMaxActiveBlocksPerMultiprocessor(
        &perCU, (const void*)archetypes_persistent, BLOCK, 0);
    const bool coop_ok = (perCU * 256 >= GRID);

    if (coop_ok) {
        void* args[] = {(void*)&x, (void*)&conn, (void*)&W_h, (void*)&W_x,
                        (void*)&bias, (void*)&inits, (void*)&outp};
        hipLaunchCooperativeKernel((void*)archetypes_persistent,
                                   dim3(GRID), dim3(BLOCK), args, 0, stream);
    } else {
        archetypes_init<<<dim3((N_ * 2 * H_ + BLOCK - 1) / BLOCK), dim3(BLOCK),
                          0, stream>>>(x, inits, outp);
        for (int t = 0; t < T_; ++t)
            archetypes_step<<<dim3(GRID), dim3(BLOCK), 0, stream>>>(
                t, x, conn, W_h, W_x, bias, outp);
    }
}

// Round 5
// 6792.098 us; speedup vs baseline: 2.9249x; 1.0452x over previous
//
#include <hip/hip_runtime.h>
#include <hip/hip_cooperative_groups.h>

namespace cg = cooperative_groups;

constexpr int   T_     = 256;
constexpr int   N_     = 64;
constexpr int   H_     = 512;
constexpr float DT_    = 0.01f;
constexpr float GAMMA_ = 1.0f;
constexpr float EPS_   = 1.0f;

constexpr int GRID  = 1024;         // 16 WGs per network, 4 WG/CU
constexpr int BLOCK = 256;          // 4 waves
constexpr int WGPN  = GRID / N_;    // 16 workgroups per network
constexpr int ROWS  = H_ / WGPN;    // 32 rows of W_h / W_x per workgroup
constexpr int RPW   = ROWS / 4;     // 8 rows per wave
constexpr int LROWS = 16;           // leading W_x rows kept LDS-resident per WG

// ---------- primary path: one persistent cooperative kernel ----------
// W_h: fully register-resident (16 float4/thread, loaded once).
// W_x: local rows [0,16) LDS-resident (32 KB), rows [16,32) streamed from L2/L3.
__global__ __launch_bounds__(BLOCK, 4)
void archetypes_persistent(const float* __restrict__ x,
                           const float* __restrict__ conn,
                           const float* __restrict__ W_h,
                           const float* __restrict__ W_x,
                           const float* __restrict__ bias,
                           const float* __restrict__ init_states,
                           float* __restrict__ out)
{
    cg::grid_group grid = cg::this_grid();

    const int tid  = threadIdx.x;
    const int wg   = blockIdx.x;
    const int n    = wg / WGPN;
    const int q    = wg % WGPN;
    const int lane = tid & 63;
    const int wave = tid >> 6;

    float* states_all = out;                                   // (T+1, N, 2, H)
    float* ins_all    = out + (size_t)(T_ + 1) * N_ * 2 * H_;  // (T+1, N, H)

    __shared__ float s_hy[H_];
    __shared__ float s_ins[H_];
    __shared__ float s_pre[ROWS];
    __shared__ float s_conn[N_];
    __shared__ float s_bias[ROWS];
    __shared__ float s_wx[LROWS][H_];   // 32 KB

    // ---- persistent W_h fragment: wave owns local rows r_l = wave + 4j ----
    const float4* Wh4 = (const float4*)(W_h + ((size_t)n * H_ + q * ROWS) * H_);
    const float4* Wx4 = (const float4*)(W_x + ((size_t)n * H_ + q * ROWS) * H_);
    float4 wh_reg[RPW][2];
    #pragma unroll
    for (int j = 0; j < RPW; ++j) {
        const int r_l = wave + 4 * j;
        #pragma unroll
        for (int k = 0; k < 2; ++k)
            wh_reg[j][k] = Wh4[r_l * (H_ / 4) + k * 64 + lane];
    }
    // ---- W_x rows [0, LROWS) into LDS (contiguous, coalesced) ----
    {
        float4* dst = (float4*)&s_wx[0][0];
        for (int idx = tid; idx < LROWS * H_ / 4; idx += BLOCK)
            dst[idx] = Wx4[idx];
    }
    if (tid < N_)   s_conn[tid] = conn[n * N_ + tid];
    if (tid < ROWS) s_bias[tid] = bias[n * H_ + q * ROWS + tid];

    // ---- t=0 outputs: states_all[0] = initial_states, ins_all[0] = x[0] ----
    for (int idx = wg * BLOCK + tid; idx < N_ * 2 * H_; idx += GRID * BLOCK)
        states_all[idx] = init_states[idx];
    for (int idx = wg * BLOCK + tid; idx < N_ * H_; idx += GRID * BLOCK)
        ins_all[idx] = x[idx];

    grid.sync();   // also orders the LDS staging for this block

    for (int t = 0; t < T_; ++t) {
        const float* st_t = states_all + (size_t)t * N_ * 2 * H_;

        // ---- Phase A: ins[h] = (conn[n,:] . hy_t[:,h]) * x_t[n,h]; 0 at t=0
        {
            const int h0 = tid, h1 = tid + 256;
            float i0 = 0.f, i1 = 0.f;
            if (t > 0) {
                const float* xr = x + (size_t)t * N_ * H_ + n * H_;
                float a0 = 0.f, a1 = 0.f;
                #pragma unroll 8
                for (int m = 0; m < N_; ++m) {
                    const float c = s_conn[m];
                    a0 += c * st_t[m * 2 * H_ + h0];
                    a1 += c * st_t[m * 2 * H_ + h1];
                }
                i0 = a0 * xr[h0];
                i1 = a1 * xr[h1];
            }
            s_ins[h0] = i0;
            s_ins[h1] = i1;
            s_hy[h0] = st_t[n * 2 * H_ + h0];
            s_hy[h1] = st_t[n * 2 * H_ + h1];
            float* insd = ins_all + (size_t)(t + 1) * N_ * H_ + n * H_;
            if (h0 / ROWS == q) insd[h0] = i0;
            if (h1 / ROWS == q) insd[h1] = i1;
        }
        __syncthreads();

        // ---- Phase B: pre[i] = W_h[i,:].hy + W_x[i,:].ins for 8 rows/wave
        {
            const float4* vh = (const float4*)s_hy;
            const float4* vi = (const float4*)s_ins;
            const float4 v0 = vh[lane], v1 = vh[64 + lane];
            const float4 u0 = vi[lane], u1 = vi[64 + lane];
            #pragma unroll
            for (int j = 0; j < RPW; ++j) {
                const int r_l = wave + 4 * j;
                float4 wx0, wx1;
                if (j < 4) {               // r_l < 16: LDS-resident W_x row
                    const float4* lx = (const float4*)&s_wx[r_l][0];
                    wx0 = lx[lane];
                    wx1 = lx[64 + lane];
                } else {                   // streamed W_x row
                    wx0 = Wx4[r_l * (H_ / 4) + lane];
                    wx1 = Wx4[r_l * (H_ / 4) + 64 + lane];
                }
                float acc = 0.f;   // same per-row arithmetic order as R4 kernel
                acc += wh_reg[j][0].x * v0.x + wh_reg[j][0].y * v0.y +
                       wh_reg[j][0].z * v0.z + wh_reg[j][0].w * v0.w;
                acc += wx0.x * u0.x + wx0.y * u0.y + wx0.z * u0.z + wx0.w * u0.w;
                acc += wh_reg[j][1].x * v1.x + wh_reg[j][1].y * v1.y +
                       wh_reg[j][1].z * v1.z + wh_reg[j][1].w * v1.w;
                acc += wx1.x * u1.x + wx1.y * u1.y + wx1.z * u1.z + wx1.w * u1.w;
                #pragma unroll
                for (int off = 32; off; off >>= 1)
                    acc += __shfl_xor(acc, off);
                if (lane == 0) s_pre[r_l] = acc;
            }
        }
        __syncthreads();

        // ---- Phase C: state update for this WG's 32 rows ----
        if (tid < ROWS) {
            const int i   = q * ROWS + tid;
            const float pre  = s_pre[tid] + s_bias[tid];
            const float hy   = st_t[n * 2 * H_ + i];
            const float hz   = st_t[n * 2 * H_ + H_ + i];
            const float th   = tanhf(pre);
            const float hz_n = hz + DT_ * (th - GAMMA_ * hy - EPS_ * hz);
            const float hy_n = hy + DT_ * hz_n;
            float* st1 = states_all + (size_t)(t + 1) * N_ * 2 * H_ + n * 2 * H_;
            st1[i]      = hy_n;
            st1[H_ + i] = hz_n;
        }

        grid.sync();   // states_all[t+1] visible to all XCDs before next step
    }
}

// ---------- fallback path: per-step kernels, stream everything ----------
__global__ __launch_bounds__(BLOCK)
void archetypes_init(const float* __restrict__ x,
                     const float* __restrict__ init_states,
                     float* __restrict__ out)
{
    float* states_all = out;
    float* ins_all    = out + (size_t)(T_ + 1) * N_ * 2 * H_;
    const int idx = blockIdx.x * BLOCK + threadIdx.x;
    if (idx < N_ * 2 * H_) states_all[idx] = init_states[idx];
    if (idx < N_ * H_)     ins_all[idx]    = x[idx];
}

__global__ __launch_bounds__(BLOCK)
void archetypes_step(int t,
                     const float* __restrict__ x,
                     const float* __restrict__ conn,
                     const float* __restrict__ W_h,
                     const float* __restrict__ W_x,
                     const float* __restrict__ bias,
                     float* __restrict__ out)
{
    const int tid  = threadIdx.x;
    const int wg   = blockIdx.x;
    const int n    = wg / WGPN;
    const int q    = wg % WGPN;
    const int lane = tid & 63;
    const int wave = tid >> 6;

    float* states_all = out;
    float* ins_all    = out + (size_t)(T_ + 1) * N_ * 2 * H_;

    __shared__ float s_hy[H_];
    __shared__ float s_ins[H_];
    __shared__ float s_pre[ROWS];
    __shared__ float s_conn[N_];
    __shared__ float s_bias[ROWS];

    if (tid < N_)   s_conn[tid] = conn[n * N_ + tid];
    if (tid < ROWS) s_bias[tid] = bias[n * H_ + q * ROWS + tid];
    __syncthreads();

    const float* st_t = states_all + (size_t)t * N_ * 2 * H_;
    {
        const int h0 = tid, h1 = tid + 256;
        float i0 = 0.f, i1 = 0.f;
        if (t > 0) {
            const float* xr = x + (size_t)t * N_ * H_ + n * H_;
            float a0 = 0.f, a1 = 0.f;
            #pragma unroll 8
            for (int m = 0; m < N_; ++m) {
                const float c = s_conn[m];
                a0 += c * st_t[m * 2 * H_ + h0];
                a1 += c * st_t[m * 2 * H_ + h1];
            }
            i0 = a0 * xr[h0];
            i1 = a1 * xr[h1];
        }
        s_ins[h0] = i0;
        s_ins[h1] = i1;
        s_hy[h0] = st_t[n * 2 * H_ + h0];
        s_hy[h1] = st_t[n * 2 * H_ + h1];
        float* insd = ins_all + (size_t)(t + 1) * N_ * H_ + n * H_;
        if (h0 / ROWS == q) insd[h0] = i0;
        if (h1 / ROWS == q) insd[h1] = i1;
    }
    __syncthreads();
    {
        const float4* vh = (const float4*)s_hy;
        const float4* vi = (const float4*)s_ins;
        const float4* Wh4 = (const float4*)(W_h + ((size_t)n * H_ + q * ROWS) * H_);
        const float4* Wx4 = (const float4*)(W_x + ((size_t)n * H_ + q * ROWS) * H_);
        const float4 v0 = vh[lane], v1 = vh[64 + lane];
        const float4 u0 = vi[lane], u1 = vi[64 + lane];
        #pragma unroll
        for (int j = 0; j < RPW; ++j) {
            const int r_l = wave + 4 * j;
            const float4 a0 = Wh4[r_l * (H_ / 4) + lane];
            const float4 a1 = Wh4[r_l * (H_ / 4) + 64 + lane];
            const float4 wx0 = Wx4[r_l * (H_ / 4) + lane];
            const float4 wx1 = Wx4[r_l * (H_ / 4) + 64 + lane];
            float acc = 0.f;
            acc += a0.x * v0.x + a0.y * v0.y + a0.z * v0.z + a0.w * v0.w;
            acc += wx0.x * u0.x + wx0.y * u0.y + wx0.z * u0.z + wx0.w * u0.w;
            acc += a1.x * v1.x + a1.y * v1.y + a1.z * v1.z + a1.w * v1.w;
            acc += wx1.x * u1.x + wx1.y * u1.y + wx1.z * u1.z + wx1.w * u1.w;
            #pragma unroll
            for (int off = 32; off; off >>= 1)
                acc += __shfl_xor(acc, off);
            if (lane == 0) s_pre[r_l] = acc;
        }
    }
    __syncthreads();
    if (tid < ROWS) {
        const int i   = q * ROWS + tid;
        const float pre  = s_pre[tid] + s_bias[tid];
        const float hy   = st_t[n * 2 * H_ + i];
        const float hz   = st_t[n * 2 * H_ + H_ + i];
        const float th   = tanhf(pre);
        const float hz_n = hz + DT_ * (th - GAMMA_ * hy - EPS_ * hz);
        const float hy_n = hy + DT_ * hz_n;
        float* st1 = states_all + (size_t)(t + 1) * N_ * 2 * H_ + n * 2 * H_;
        st1[i]      = hy_n;
        st1[H_ + i] = hz_n;
    }
}

extern "C" void kernel_launch(void* const* d_in, const int* in_sizes, int n_in,
                              void* d_out, int out_size, void* d_ws, size_t ws_size,
                              hipStream_t stream) {
    const float* x     = (const float*)d_in[0];
    const float* conn  = (const float*)d_in[1];
    const float* W_h   = (const float*)d_in[2];
    const float* W_x   = (const float*)d_in[3];
    const float* bias  = (const float*)d_in[4];
    const float* inits = (const float*)d_in[5];
    float*       outp  = (float*)d_out;

    // Capture-safe, deterministic host-side occupancy gate: only take the
    // cooperative path if all GRID WGs are provably co-resident.
    int perCU = 0;
    (void)hipOccupancyMaxActiveBlocksPerMultiprocessor(
        &perCU, (const void*)archetypes_persistent, BLOCK, 0);
    const bool coop_ok = (perCU * 256 >= GRID);

    if (coop_ok) {
        void* args[] = {(void*)&x, (void*)&conn, (void*)&W_h, (void*)&W_x,
                        (void*)&bias, (void*)&inits, (void*)&outp};
        hipLaunchCooperativeKernel((void*)archetypes_persistent,
                                   dim3(GRID), dim3(BLOCK), args, 0, stream);
    } else {
        archetypes_init<<<dim3((N_ * 2 * H_ + BLOCK - 1) / BLOCK), dim3(BLOCK),
                          0, stream>>>(x, inits, outp);
        for (int t = 0; t < T_; ++t)
            archetypes_step<<<dim3(GRID), dim3(BLOCK), 0, stream>>>(
                t, x, conn, W_h, W_x, bias, outp);
    }
}

// Round 6
// 6729.960 us; speedup vs baseline: 2.9519x; 1.0092x over previous
//
#include <hip/hip_runtime.h>

constexpr int   T_ = 256, N_ = 64, H_ = 512;
constexpr float DT_ = 0.01f, GAMMA_ = 1.0f, EPS_ = 1.0f;

constexpr int GRID  = 256;           // 1 WG/CU
constexpr int BLOCK = 1024;          // 16 waves
constexpr int WGPN  = GRID / N_;     // 4 WGs per network
constexpr int ROWS  = H_ / WGPN;     // 128 rows per WG
constexpr int WAVES = BLOCK / 64;    // 16
constexpr int RPW   = ROWS / WAVES;  // 8 rows per wave
constexpr int LJ    = 4;             // j<LJ: W_x row in LDS; j>=LJ: registers

// Lightweight grid barrier: release-fence + arrival counter + generation spin.
// Semantically equivalent to cg::grid_group::sync() (device-scope acq/rel),
// but leaner. State: bar[0]=counter, bar[1]=generation (zeroed by memset).
__device__ __forceinline__ void grid_barrier(unsigned* cnt, unsigned* gen,
                                             unsigned target) {
    __syncthreads();
    if (threadIdx.x == 0) {
        __threadfence();   // release: my global writes visible device-wide
        unsigned prev = __hip_atomic_fetch_add(cnt, 1u, __ATOMIC_ACQ_REL,
                                               __HIP_MEMORY_SCOPE_AGENT);
        if (prev == (unsigned)GRID - 1u) {
            __hip_atomic_store(cnt, 0u, __ATOMIC_RELAXED,
                               __HIP_MEMORY_SCOPE_AGENT);
            __hip_atomic_fetch_add(gen, 1u, __ATOMIC_RELEASE,
                                   __HIP_MEMORY_SCOPE_AGENT);
        } else {
            while (__hip_atomic_load(gen, __ATOMIC_ACQUIRE,
                                     __HIP_MEMORY_SCOPE_AGENT) < target)
                __builtin_amdgcn_s_sleep(1);
        }
    }
    __syncthreads();
    __threadfence();       // acquire: discard stale cached state
}

// ---------- primary path: one persistent cooperative kernel ----------
// W_h: all 128 rows/WG register-resident (64 VGPR/thread).
// W_x: rows [0,64) in 128 KB LDS, rows [64,128) register-resident (32 VGPR).
// Zero weight traffic in the steady state.
__global__ __launch_bounds__(BLOCK, 4)
void archetypes_persistent(const float* __restrict__ x,
                           const float* __restrict__ conn,
                           const float* __restrict__ W_h,
                           const float* __restrict__ W_x,
                           const float* __restrict__ bias,
                           const float* __restrict__ init_states,
                           float* __restrict__ out,
                           unsigned* __restrict__ bar)
{
    const int tid  = threadIdx.x;
    const int wg   = blockIdx.x;
    const int n    = wg / WGPN;
    const int q    = wg % WGPN;
    const int lane = tid & 63;
    const int wave = tid >> 6;

    float* states_all = out;                                   // (T+1, N, 2, H)
    float* ins_all    = out + (size_t)(T_ + 1) * N_ * 2 * H_;  // (T+1, N, H)

    __shared__ float s_wx[LJ * WAVES][H_];   // 64 W_x rows, 128 KB
    __shared__ float s_hy[H_];
    __shared__ float s_ins[H_];
    __shared__ float s_pre[ROWS];
    __shared__ float s_conn[N_];
    __shared__ float s_bias[ROWS];

    const float4* Wh4 = (const float4*)(W_h + ((size_t)n * H_ + q * ROWS) * H_);
    const float4* Wx4 = (const float4*)(W_x + ((size_t)n * H_ + q * ROWS) * H_);

    // persistent weight fragments: wave owns local rows r_l = wave + 16*j
    float4 wh_reg[RPW][2];
    float4 wx_reg[RPW - LJ][2];
    #pragma unroll
    for (int j = 0; j < RPW; ++j) {
        const int r_l = wave + WAVES * j;
        wh_reg[j][0] = Wh4[r_l * (H_ / 4) + lane];
        wh_reg[j][1] = Wh4[r_l * (H_ / 4) + 64 + lane];
    }
    #pragma unroll
    for (int j = LJ; j < RPW; ++j) {
        const int r_l = wave + WAVES * j;
        wx_reg[j - LJ][0] = Wx4[r_l * (H_ / 4) + lane];
        wx_reg[j - LJ][1] = Wx4[r_l * (H_ / 4) + 64 + lane];
    }
    // W_x rows [0,64) -> LDS (contiguous, coalesced)
    {
        float4* dst = (float4*)&s_wx[0][0];
        for (int idx = tid; idx < LJ * WAVES * (H_ / 4); idx += BLOCK)
            dst[idx] = Wx4[idx];
    }
    if (tid < N_)   s_conn[tid] = conn[n * N_ + tid];
    if (tid < ROWS) s_bias[tid] = bias[n * H_ + q * ROWS + tid];

    // ---- t=0 outputs ----
    for (int idx = wg * BLOCK + tid; idx < N_ * 2 * H_; idx += GRID * BLOCK)
        states_all[idx] = init_states[idx];
    for (int idx = wg * BLOCK + tid; idx < N_ * H_; idx += GRID * BLOCK)
        ins_all[idx] = x[idx];

    unsigned* cnt = bar;
    unsigned* gen = bar + 1;
    unsigned bt = 0;

    grid_barrier(cnt, gen, ++bt);

    const int half = tid >> 9;        // 0: conn-dot half, 1: s_hy staging half
    const int h    = tid & (H_ - 1);

    for (int t = 0; t < T_; ++t) {
        const float* st_t = states_all + (size_t)t * N_ * 2 * H_;

        // ---- Phase A: lower 512 threads do the full conn-dot for their h
        //      (same sequential m-order as prior passing kernels); upper 512
        //      threads concurrently stage s_hy.
        if (!half) {
            float i0 = 0.f;
            if (t > 0) {
                float a = 0.f;
                #pragma unroll 8
                for (int m = 0; m < N_; ++m)
                    a += s_conn[m] * st_t[m * 2 * H_ + h];
                i0 = a * x[(size_t)t * N_ * H_ + n * H_ + h];
            }
            s_ins[h] = i0;
            float* insd = ins_all + (size_t)(t + 1) * N_ * H_ + n * H_;
            if (h / ROWS == q) insd[h] = i0;
        } else {
            s_hy[h] = st_t[n * 2 * H_ + h];
        }
        __syncthreads();

        // ---- Phase B: pre[i] = W_h[i,:].hy + W_x[i,:].ins, 8 rows/wave ----
        {
            const float4* vh = (const float4*)s_hy;
            const float4* vi = (const float4*)s_ins;
            const float4 v0 = vh[lane], v1 = vh[64 + lane];
            const float4 u0 = vi[lane], u1 = vi[64 + lane];
            #pragma unroll
            for (int j = 0; j < RPW; ++j) {
                const int r_l = wave + WAVES * j;
                float4 wx0, wx1;
                if (j < LJ) {                  // LDS-resident W_x row
                    const float4* lx = (const float4*)&s_wx[r_l][0];
                    wx0 = lx[lane];
                    wx1 = lx[64 + lane];
                } else {                       // register-resident W_x row
                    wx0 = wx_reg[j - LJ][0];
                    wx1 = wx_reg[j - LJ][1];
                }
                float acc = 0.f;   // same per-row FP order as passing kernels
                acc += wh_reg[j][0].x * v0.x + wh_reg[j][0].y * v0.y +
                       wh_reg[j][0].z * v0.z + wh_reg[j][0].w * v0.w;
                acc += wx0.x * u0.x + wx0.y * u0.y + wx0.z * u0.z + wx0.w * u0.w;
                acc += wh_reg[j][1].x * v1.x + wh_reg[j][1].y * v1.y +
                       wh_reg[j][1].z * v1.z + wh_reg[j][1].w * v1.w;
                acc += wx1.x * u1.x + wx1.y * u1.y + wx1.z * u1.z + wx1.w * u1.w;
                #pragma unroll
                for (int off = 32; off; off >>= 1)
                    acc += __shfl_xor(acc, off);
                if (lane == 0) s_pre[r_l] = acc;
            }
        }
        __syncthreads();

        // ---- Phase C: state update for this WG's 128 rows ----
        if (tid < ROWS) {
            const int i    = q * ROWS + tid;
            const float pre  = s_pre[tid] + s_bias[tid];
            const float hy   = s_hy[i];
            const float hz   = st_t[n * 2 * H_ + H_ + i];
            const float th   = tanhf(pre);
            const float hz_n = hz + DT_ * (th - GAMMA_ * hy - EPS_ * hz);
            const float hy_n = hy + DT_ * hz_n;
            float* st1 = states_all + (size_t)(t + 1) * N_ * 2 * H_ + n * 2 * H_;
            st1[i]      = hy_n;
            st1[H_ + i] = hz_n;
        }

        grid_barrier(cnt, gen, ++bt);
    }
}

// ---------- fallback path: per-step kernels, stream-ordered ----------
constexpr int FGRID = 1024, FBLOCK = 256, FWGPN = 16, FROWS = 32, FRPW = 8;

__global__ __launch_bounds__(FBLOCK)
void archetypes_init(const float* __restrict__ x,
                     const float* __restrict__ init_states,
                     float* __restrict__ out)
{
    float* states_all = out;
    float* ins_all    = out + (size_t)(T_ + 1) * N_ * 2 * H_;
    const int idx = blockIdx.x * FBLOCK + threadIdx.x;
    if (idx < N_ * 2 * H_) states_all[idx] = init_states[idx];
    if (idx < N_ * H_)     ins_all[idx]    = x[idx];
}

__global__ __launch_bounds__(FBLOCK)
void archetypes_step(int t,
                     const float* __restrict__ x,
                     const float* __restrict__ conn,
                     const float* __restrict__ W_h,
                     const float* __restrict__ W_x,
                     const float* __restrict__ bias,
                     float* __restrict__ out)
{
    const int tid  = threadIdx.x;
    const int wg   = blockIdx.x;
    const int n    = wg / FWGPN;
    const int q    = wg % FWGPN;
    const int lane = tid & 63;
    const int wave = tid >> 6;

    float* states_all = out;
    float* ins_all    = out + (size_t)(T_ + 1) * N_ * 2 * H_;

    __shared__ float s_hy[H_];
    __shared__ float s_ins[H_];
    __shared__ float s_pre[FROWS];
    __shared__ float s_conn[N_];
    __shared__ float s_bias[FROWS];

    if (tid < N_)    s_conn[tid] = conn[n * N_ + tid];
    if (tid < FROWS) s_bias[tid] = bias[n * H_ + q * FROWS + tid];
    __syncthreads();

    const float* st_t = states_all + (size_t)t * N_ * 2 * H_;
    {
        const int h0 = tid, h1 = tid + 256;
        float i0 = 0.f, i1 = 0.f;
        if (t > 0) {
            const float* xr = x + (size_t)t * N_ * H_ + n * H_;
            float a0 = 0.f, a1 = 0.f;
            #pragma unroll 8
            for (int m = 0; m < N_; ++m) {
                const float c = s_conn[m];
                a0 += c * st_t[m * 2 * H_ + h0];
                a1 += c * st_t[m * 2 * H_ + h1];
            }
            i0 = a0 * xr[h0];
            i1 = a1 * xr[h1];
        }
        s_ins[h0] = i0;
        s_ins[h1] = i1;
        s_hy[h0] = st_t[n * 2 * H_ + h0];
        s_hy[h1] = st_t[n * 2 * H_ + h1];
        float* insd = ins_all + (size_t)(t + 1) * N_ * H_ + n * H_;
        if (h0 / FROWS == q) insd[h0] = i0;
        if (h1 / FROWS == q) insd[h1] = i1;
    }
    __syncthreads();
    {
        const float4* vh = (const float4*)s_hy;
        const float4* vi = (const float4*)s_ins;
        const float4* Wh4 = (const float4*)(W_h + ((size_t)n * H_ + q * FROWS) * H_);
        const float4* Wx4 = (const float4*)(W_x + ((size_t)n * H_ + q * FROWS) * H_);
        const float4 v0 = vh[lane], v1 = vh[64 + lane];
        const float4 u0 = vi[lane], u1 = vi[64 + lane];
        #pragma unroll
        for (int j = 0; j < FRPW; ++j) {
            const int r_l = wave + 4 * j;
            const float4 a0 = Wh4[r_l * (H_ / 4) + lane];
            const float4 a1 = Wh4[r_l * (H_ / 4) + 64 + lane];
            const float4 wx0 = Wx4[r_l * (H_ / 4) + lane];
            const float4 wx1 = Wx4[r_l * (H_ / 4) + 64 + lane];
            float acc = 0.f;
            acc += a0.x * v0.x + a0.y * v0.y + a0.z * v0.z + a0.w * v0.w;
            acc += wx0.x * u0.x + wx0.y * u0.y + wx0.z * u0.z + wx0.w * u0.w;
            acc += a1.x * v1.x + a1.y * v1.y + a1.z * v1.z + a1.w * v1.w;
            acc += wx1.x * u1.x + wx1.y * u1.y + wx1.z * u1.z + wx1.w * u1.w;
            #pragma unroll
            for (int off = 32; off; off >>= 1)
                acc += __shfl_xor(acc, off);
            if (lane == 0) s_pre[r_l] = acc;
        }
    }
    __syncthreads();
    if (tid < FROWS) {
        const int i   = q * FROWS + tid;
        const float pre  = s_pre[tid] + s_bias[tid];
        const float hy   = st_t[n * 2 * H_ + i];
        const float hz   = st_t[n * 2 * H_ + H_ + i];
        const float th   = tanhf(pre);
        const float hz_n = hz + DT_ * (th - GAMMA_ * hy - EPS_ * hz);
        const float hy_n = hy + DT_ * hz_n;
        float* st1 = states_all + (size_t)(t + 1) * N_ * 2 * H_ + n * 2 * H_;
        st1[i]      = hy_n;
        st1[H_ + i] = hz_n;
    }
}

extern "C" void kernel_launch(void* const* d_in, const int* in_sizes, int n_in,
                              void* d_out, int out_size, void* d_ws, size_t ws_size,
                              hipStream_t stream) {
    const float* x     = (const float*)d_in[0];
    const float* conn  = (const float*)d_in[1];
    const float* W_h   = (const float*)d_in[2];
    const float* W_x   = (const float*)d_in[3];
    const float* bias  = (const float*)d_in[4];
    const float* inits = (const float*)d_in[5];
    float*       outp  = (float*)d_out;
    unsigned*    bar   = (unsigned*)d_ws;

    // Capture-safe, deterministic host-side occupancy gate: only take the
    // cooperative path if all GRID WGs are provably co-resident.
    int perCU = 0;
    (void)hipOccupancyMaxActiveBlocksPerMultiprocessor(
        &perCU, (const void*)archetypes_persistent, BLOCK, 0);
    const bool coop_ok = (perCU * 256 >= GRID);

    if (coop_ok) {
        hipMemsetAsync(bar, 0, 2 * sizeof(unsigned), stream);  // barrier state
        void* args[] = {(void*)&x, (void*)&conn, (void*)&W_h, (void*)&W_x,
                        (void*)&bias, (void*)&inits, (void*)&outp, (void*)&bar};
        hipLaunchCooperativeKernel((void*)archetypes_persistent,
                                   dim3(GRID), dim3(BLOCK), args, 0, stream);
    } else {
        archetypes_init<<<dim3((N_ * 2 * H_ + FBLOCK - 1) / FBLOCK), dim3(FBLOCK),
                          0, stream>>>(x, inits, outp);
        for (int t = 0; t < T_; ++t)
            archetypes_step<<<dim3(FGRID), dim3(FBLOCK), 0, stream>>>(
                t, x, conn, W_h, W_x, bias, outp);
    }
}